// Round 2
// baseline (139.927 us; speedup 1.0000x reference)
//
#include <hip/hip_runtime.h>

#define HH 160
#define WW 160
#define DD 16
#define NG 8192
#define VOXEL 0.4f

// tiles: 20 x 20 x 4 (each 8x8x4 voxels) = 1600 tiles
#define TTX 20
#define TTY 20
#define TTZ 4
#define NTILES (TTX * TTY * TTZ)
#define CAP 256   // max survivors per tile (expected ~44, Poisson max ~90)

// d_ws layout:
//   pack     : 8192 * 4 float4 (64 B/gaussian)           = 512 KB
//   tileCnt  : NTILES int                                 @ 512 KB
//   tileList : NTILES * CAP int                           @ 520 KB (1.6 MB)
// pack per gaussian:
//   p0 = (mu.x, mu.y, mu.z, opacity)
//   p1 = (3sx,  3sy,  3sz,  ci00)
//   p2 = (ci01, ci02, ci11, ci12)
//   p3 = (ci22, 0, 0, 0)

__global__ __launch_bounds__(256) void gv_precompute_bin(
    const float* __restrict__ means, const float* __restrict__ opac,
    const float* __restrict__ scales, const float* __restrict__ rots,
    float4* __restrict__ pack, int* __restrict__ tileCnt,
    int* __restrict__ tileList) {
  int g = blockIdx.x * 256 + threadIdx.x;
  if (g >= NG) return;
  float qw = rots[g * 4 + 0], qx = rots[g * 4 + 1];
  float qy = rots[g * 4 + 2], qz = rots[g * 4 + 3];
  float inv = rsqrtf(qw * qw + qx * qx + qy * qy + qz * qz);
  qw *= inv; qx *= inv; qy *= inv; qz *= inv;
  float R[3][3];
  R[0][0] = 1.f - 2.f * (qy * qy + qz * qz);
  R[0][1] = 2.f * (qx * qy - qw * qz);
  R[0][2] = 2.f * (qx * qz + qw * qy);
  R[1][0] = 2.f * (qx * qy + qw * qz);
  R[1][1] = 1.f - 2.f * (qx * qx + qz * qz);
  R[1][2] = 2.f * (qy * qz - qw * qx);
  R[2][0] = 2.f * (qx * qz - qw * qy);
  R[2][1] = 2.f * (qy * qz + qw * qx);
  R[2][2] = 1.f - 2.f * (qx * qx + qy * qy);
  float sx = scales[g * 3 + 0], sy = scales[g * 3 + 1], sz = scales[g * 3 + 2];
  float s2[3] = {sx * sx, sy * sy, sz * sz};
  float is2[3] = {1.f / s2[0], 1.f / s2[1], 1.f / s2[2]};
  float cov00 = 0.f, cov11 = 0.f, cov22 = 0.f;
  float ci00 = 0.f, ci01 = 0.f, ci02 = 0.f, ci11 = 0.f, ci12 = 0.f, ci22 = 0.f;
#pragma unroll
  for (int c = 0; c < 3; c++) {
    cov00 += R[0][c] * R[0][c] * s2[c];
    cov11 += R[1][c] * R[1][c] * s2[c];
    cov22 += R[2][c] * R[2][c] * s2[c];
    ci00 += R[0][c] * R[0][c] * is2[c];
    ci01 += R[0][c] * R[1][c] * is2[c];
    ci02 += R[0][c] * R[2][c] * is2[c];
    ci11 += R[1][c] * R[1][c] * is2[c];
    ci12 += R[1][c] * R[2][c] * is2[c];
    ci22 += R[2][c] * R[2][c] * is2[c];
  }
  float mx = means[g * 3 + 0], my = means[g * 3 + 1], mz = means[g * 3 + 2];
  float bx = 3.f * sqrtf(cov00), by = 3.f * sqrtf(cov11), bz = 3.f * sqrtf(cov22);
  float4* p = pack + (size_t)g * 4;
  p[0] = make_float4(mx, my, mz, opac[g]);
  p[1] = make_float4(bx, by, bz, ci00);
  p[2] = make_float4(ci01, ci02, ci11, ci12);
  p[3] = make_float4(ci22, 0.f, 0.f, 0.f);

  // voxel-center index ranges covered by bbox (with float-slop margin)
  const float eps = 1e-4f;
  int i0 = (int)ceilf((mx - bx + 32.f) * 2.5f - 0.5f - eps);
  int i1 = (int)floorf((mx + bx + 32.f) * 2.5f - 0.5f + eps);
  int j0 = (int)ceilf((my - by + 32.f) * 2.5f - 0.5f - eps);
  int j1 = (int)floorf((my + by + 32.f) * 2.5f - 0.5f + eps);
  int k0 = (int)ceilf((mz - bz + 1.f) * 2.5f - 0.5f - eps);
  int k1 = (int)floorf((mz + bz + 1.f) * 2.5f - 0.5f + eps);
  i0 = max(i0, 0); i1 = min(i1, HH - 1);
  j0 = max(j0, 0); j1 = min(j1, WW - 1);
  k0 = max(k0, 0); k1 = min(k1, DD - 1);
  if (i0 > i1 || j0 > j1 || k0 > k1) return;
  int ti0 = i0 >> 3, ti1 = i1 >> 3;
  int tj0 = j0 >> 3, tj1 = j1 >> 3;
  int tk0 = k0 >> 2, tk1 = k1 >> 2;
  for (int ti = ti0; ti <= ti1; ti++)
    for (int tj = tj0; tj <= tj1; tj++)
      for (int tk = tk0; tk <= tk1; tk++) {
        int t = (ti * TTY + tj) * TTZ + tk;
        int pos = atomicAdd(&tileCnt[t], 1);
        if (pos < CAP) tileList[t * CAP + pos] = g;
      }
}

// Voxelize: all inner-loop gaussian data is WAVE-UNIFORM. Force uniformity
// with readfirstlane so the backend scalarizes pack/feat loads into
// s_load_dwordx16 (SGPR broadcast) instead of pushing 1 KB/instr through
// the LDS pipe. No LDS, no __syncthreads, no staging stores.
__global__ __launch_bounds__(256) void gv_voxelize(
    const float4* __restrict__ pack, const float4* __restrict__ feats,
    const int* __restrict__ tileCnt, const int* __restrict__ tileList,
    float4* __restrict__ out) {
  int tid = threadIdx.x;
  int dk = tid & 3, dj = (tid >> 2) & 7, di = tid >> 5;
  int tk = blockIdx.x, tj = blockIdx.y, ti = blockIdx.z;
  int i = ti * 8 + di, j = tj * 8 + dj, k = tk * 4 + dk;

  float px = (i + 0.5f) * VOXEL - 32.f;
  float py = (j + 0.5f) * VOXEL - 32.f;
  float pz = (k + 0.5f) * VOXEL - 1.f;

  int t = (ti * TTY + tj) * TTZ + tk;
  int cnt = tileCnt[t];
  cnt = min(cnt, CAP);
  const int* __restrict__ lst = tileList + t * CAP;

  float4 acc[8];
#pragma unroll
  for (int f = 0; f < 8; f++) acc[f] = make_float4(0.f, 0.f, 0.f, 0.f);

  for (int n = 0; n < cnt; n++) {
    int gg = __builtin_amdgcn_readfirstlane(lst[n]);
    const float4* __restrict__ p = pack + (size_t)gg * 4;
    float4 pa = p[0];
    float4 pb = p[1];
    float dx = px - pa.x, dy = py - pa.y, dz = pz - pa.z;
    bool in = (fabsf(dx) <= pb.x) & (fabsf(dy) <= pb.y) & (fabsf(dz) <= pb.z);
    if (__any(in)) {
      float4 pc = p[2];
      float4 pd = p[3];
      float maha = pb.w * dx * dx + pc.z * dy * dy + pd.x * dz * dz +
                   2.f * (pc.x * dx * dy + pc.y * dx * dz + pc.w * dy * dz);
      float w = in ? pa.w * __expf(-0.5f * maha) : 0.f;
      const float4* __restrict__ fp = feats + (size_t)gg * 8;
#pragma unroll
      for (int f = 0; f < 8; f++) {
        float4 fv = fp[f];
        acc[f].x += w * fv.x;
        acc[f].y += w * fv.y;
        acc[f].z += w * fv.z;
        acc[f].w += w * fv.w;
      }
    }
  }

  size_t v = ((size_t)i * WW + j) * DD + k;
  float4* o = out + v * 8;
#pragma unroll
  for (int f = 0; f < 8; f++) o[f] = acc[f];
}

extern "C" void kernel_launch(void* const* d_in, const int* in_sizes, int n_in,
                              void* d_out, int out_size, void* d_ws, size_t ws_size,
                              hipStream_t stream) {
  const float* means  = (const float*)d_in[0];
  const float* opac   = (const float*)d_in[1];
  const float* scales = (const float*)d_in[2];
  const float* rots   = (const float*)d_in[3];
  const float4* feats = (const float4*)d_in[4];

  char* ws = (char*)d_ws;
  float4* pack   = (float4*)ws;                       // 512 KB
  int* tileCnt   = (int*)(ws + 512 * 1024);           // 6.4 KB
  int* tileList  = (int*)(ws + 520 * 1024);           // 1.6 MB

  hipMemsetAsync(tileCnt, 0, NTILES * sizeof(int), stream);
  gv_precompute_bin<<<32, 256, 0, stream>>>(means, opac, scales, rots,
                                            pack, tileCnt, tileList);
  dim3 grid(TTZ, TTY, TTX);
  gv_voxelize<<<grid, 256, 0, stream>>>(pack, feats, tileCnt, tileList,
                                        (float4*)d_out);
}

// Round 3
// 128.920 us; speedup vs baseline: 1.0854x; 1.0854x over previous
//
#include <hip/hip_runtime.h>

#define HH 160
#define WW 160
#define DD 16
#define NG 8192
#define VOXEL 0.4f

// tiles: 20 x 20 x 4 (each 8x8x4 voxels) = 1600 tiles
#define TTX 20
#define TTY 20
#define TTZ 4
#define NTILES (TTX * TTY * TTZ)
#define CAP 256   // max survivors per tile (expected ~44, Poisson max ~90)

// d_ws layout:
//   pack     : 8192 * 4 float4 (64 B/gaussian)           = 512 KB
//   tileCnt  : NTILES int                                 @ 512 KB
//   tileList : NTILES * CAP int                           @ 520 KB (1.6 MB)
// pack per gaussian:
//   p0 = (mu.x, mu.y, mu.z, opacity)
//   p1 = (3sx,  3sy,  3sz,  ci00)
//   p2 = (ci01, ci02, ci11, ci12)
//   p3 = (ci22, 0, 0, 0)

__global__ __launch_bounds__(64) void gv_precompute_bin(
    const float* __restrict__ means, const float* __restrict__ opac,
    const float* __restrict__ scales, const float* __restrict__ rots,
    float4* __restrict__ pack, int* __restrict__ tileCnt,
    int* __restrict__ tileList) {
  int g = blockIdx.x * 64 + threadIdx.x;
  if (g >= NG) return;
  float qw = rots[g * 4 + 0], qx = rots[g * 4 + 1];
  float qy = rots[g * 4 + 2], qz = rots[g * 4 + 3];
  float inv = rsqrtf(qw * qw + qx * qx + qy * qy + qz * qz);
  qw *= inv; qx *= inv; qy *= inv; qz *= inv;
  float R[3][3];
  R[0][0] = 1.f - 2.f * (qy * qy + qz * qz);
  R[0][1] = 2.f * (qx * qy - qw * qz);
  R[0][2] = 2.f * (qx * qz + qw * qy);
  R[1][0] = 2.f * (qx * qy + qw * qz);
  R[1][1] = 1.f - 2.f * (qx * qx + qz * qz);
  R[1][2] = 2.f * (qy * qz - qw * qx);
  R[2][0] = 2.f * (qx * qz - qw * qy);
  R[2][1] = 2.f * (qy * qz + qw * qx);
  R[2][2] = 1.f - 2.f * (qx * qx + qy * qy);
  float sx = scales[g * 3 + 0], sy = scales[g * 3 + 1], sz = scales[g * 3 + 2];
  float s2[3] = {sx * sx, sy * sy, sz * sz};
  float is2[3] = {1.f / s2[0], 1.f / s2[1], 1.f / s2[2]};
  float cov00 = 0.f, cov11 = 0.f, cov22 = 0.f;
  float ci00 = 0.f, ci01 = 0.f, ci02 = 0.f, ci11 = 0.f, ci12 = 0.f, ci22 = 0.f;
#pragma unroll
  for (int c = 0; c < 3; c++) {
    cov00 += R[0][c] * R[0][c] * s2[c];
    cov11 += R[1][c] * R[1][c] * s2[c];
    cov22 += R[2][c] * R[2][c] * s2[c];
    ci00 += R[0][c] * R[0][c] * is2[c];
    ci01 += R[0][c] * R[1][c] * is2[c];
    ci02 += R[0][c] * R[2][c] * is2[c];
    ci11 += R[1][c] * R[1][c] * is2[c];
    ci12 += R[1][c] * R[2][c] * is2[c];
    ci22 += R[2][c] * R[2][c] * is2[c];
  }
  float mx = means[g * 3 + 0], my = means[g * 3 + 1], mz = means[g * 3 + 2];
  float bx = 3.f * sqrtf(cov00), by = 3.f * sqrtf(cov11), bz = 3.f * sqrtf(cov22);
  float4* p = pack + (size_t)g * 4;
  p[0] = make_float4(mx, my, mz, opac[g]);
  p[1] = make_float4(bx, by, bz, ci00);
  p[2] = make_float4(ci01, ci02, ci11, ci12);
  p[3] = make_float4(ci22, 0.f, 0.f, 0.f);

  // voxel-center index ranges covered by bbox (with float-slop margin)
  const float eps = 1e-4f;
  int i0 = (int)ceilf((mx - bx + 32.f) * 2.5f - 0.5f - eps);
  int i1 = (int)floorf((mx + bx + 32.f) * 2.5f - 0.5f + eps);
  int j0 = (int)ceilf((my - by + 32.f) * 2.5f - 0.5f - eps);
  int j1 = (int)floorf((my + by + 32.f) * 2.5f - 0.5f + eps);
  int k0 = (int)ceilf((mz - bz + 1.f) * 2.5f - 0.5f - eps);
  int k1 = (int)floorf((mz + bz + 1.f) * 2.5f - 0.5f + eps);
  i0 = max(i0, 0); i1 = min(i1, HH - 1);
  j0 = max(j0, 0); j1 = min(j1, WW - 1);
  k0 = max(k0, 0); k1 = min(k1, DD - 1);
  if (i0 > i1 || j0 > j1 || k0 > k1) return;
  int ti0 = i0 >> 3, ti1 = i1 >> 3;
  int tj0 = j0 >> 3, tj1 = j1 >> 3;
  int tk0 = k0 >> 2, tk1 = k1 >> 2;
  for (int ti = ti0; ti <= ti1; ti++)
    for (int tj = tj0; tj <= tj1; tj++)
      for (int tk = tk0; tk <= tk1; tk++) {
        int t = (ti * TTY + tj) * TTZ + tk;
        int pos = atomicAdd(&tileCnt[t], 1);
        if (pos < CAP) tileList[t * CAP + pos] = g;
      }
}

// Voxelize: all gaussian data is wave-uniform -> scalar (SGPR) loads.
// Inner loop is 2-way unrolled over gaussians so the two scalar-load
// dependency chains (lst[n] -> pack[gg] -> maha -> feats) overlap,
// halving exposed SMEM latency per gaussian.
__global__ __launch_bounds__(256) void gv_voxelize(
    const float4* __restrict__ pack, const float4* __restrict__ feats,
    const int* __restrict__ tileCnt, const int* __restrict__ tileList,
    float4* __restrict__ out) {
  int tid = threadIdx.x;
  int dk = tid & 3, dj = (tid >> 2) & 7, di = tid >> 5;
  int tk = blockIdx.x, tj = blockIdx.y, ti = blockIdx.z;
  int i = ti * 8 + di, j = tj * 8 + dj, k = tk * 4 + dk;

  float px = (i + 0.5f) * VOXEL - 32.f;
  float py = (j + 0.5f) * VOXEL - 32.f;
  float pz = (k + 0.5f) * VOXEL - 1.f;

  int t = (ti * TTY + tj) * TTZ + tk;
  int cnt = tileCnt[t];
  cnt = min(cnt, CAP);
  const int* __restrict__ lst = tileList + t * CAP;

  float4 acc[8];
#pragma unroll
  for (int f = 0; f < 8; f++) acc[f] = make_float4(0.f, 0.f, 0.f, 0.f);

  int n = 0;
  for (; n + 2 <= cnt; n += 2) {
    int g0 = __builtin_amdgcn_readfirstlane(lst[n]);
    int g1 = __builtin_amdgcn_readfirstlane(lst[n + 1]);
    const float4* __restrict__ p0 = pack + (size_t)g0 * 4;
    const float4* __restrict__ p1 = pack + (size_t)g1 * 4;
    // issue both pack loads before either is consumed
    float4 a0 = p0[0], b0 = p0[1], c0 = p0[2], d0 = p0[3];
    float4 a1 = p1[0], b1 = p1[1], c1 = p1[2], d1 = p1[3];

    float dx0 = px - a0.x, dy0 = py - a0.y, dz0 = pz - a0.z;
    float dx1 = px - a1.x, dy1 = py - a1.y, dz1 = pz - a1.z;
    bool in0 = (fabsf(dx0) <= b0.x) & (fabsf(dy0) <= b0.y) & (fabsf(dz0) <= b0.z);
    bool in1 = (fabsf(dx1) <= b1.x) & (fabsf(dy1) <= b1.y) & (fabsf(dz1) <= b1.z);

    if (__any(in0)) {
      float maha = b0.w * dx0 * dx0 + c0.z * dy0 * dy0 + d0.x * dz0 * dz0 +
                   2.f * (c0.x * dx0 * dy0 + c0.y * dx0 * dz0 + c0.w * dy0 * dz0);
      float w = in0 ? a0.w * __expf(-0.5f * maha) : 0.f;
      const float4* __restrict__ fp = feats + (size_t)g0 * 8;
#pragma unroll
      for (int f = 0; f < 8; f++) {
        float4 fv = fp[f];
        acc[f].x += w * fv.x;
        acc[f].y += w * fv.y;
        acc[f].z += w * fv.z;
        acc[f].w += w * fv.w;
      }
    }
    if (__any(in1)) {
      float maha = b1.w * dx1 * dx1 + c1.z * dy1 * dy1 + d1.x * dz1 * dz1 +
                   2.f * (c1.x * dx1 * dy1 + c1.y * dx1 * dz1 + c1.w * dy1 * dz1);
      float w = in1 ? a1.w * __expf(-0.5f * maha) : 0.f;
      const float4* __restrict__ fp = feats + (size_t)g1 * 8;
#pragma unroll
      for (int f = 0; f < 8; f++) {
        float4 fv = fp[f];
        acc[f].x += w * fv.x;
        acc[f].y += w * fv.y;
        acc[f].z += w * fv.z;
        acc[f].w += w * fv.w;
      }
    }
  }
  if (n < cnt) {
    int gg = __builtin_amdgcn_readfirstlane(lst[n]);
    const float4* __restrict__ p = pack + (size_t)gg * 4;
    float4 pa = p[0], pb = p[1];
    float dx = px - pa.x, dy = py - pa.y, dz = pz - pa.z;
    bool in = (fabsf(dx) <= pb.x) & (fabsf(dy) <= pb.y) & (fabsf(dz) <= pb.z);
    if (__any(in)) {
      float4 pc = p[2], pd = p[3];
      float maha = pb.w * dx * dx + pc.z * dy * dy + pd.x * dz * dz +
                   2.f * (pc.x * dx * dy + pc.y * dx * dz + pc.w * dy * dz);
      float w = in ? pa.w * __expf(-0.5f * maha) : 0.f;
      const float4* __restrict__ fp = feats + (size_t)gg * 8;
#pragma unroll
      for (int f = 0; f < 8; f++) {
        float4 fv = fp[f];
        acc[f].x += w * fv.x;
        acc[f].y += w * fv.y;
        acc[f].z += w * fv.z;
        acc[f].w += w * fv.w;
      }
    }
  }

  size_t v = ((size_t)i * WW + j) * DD + k;
  float4* o = out + v * 8;
#pragma unroll
  for (int f = 0; f < 8; f++) o[f] = acc[f];
}

extern "C" void kernel_launch(void* const* d_in, const int* in_sizes, int n_in,
                              void* d_out, int out_size, void* d_ws, size_t ws_size,
                              hipStream_t stream) {
  const float* means  = (const float*)d_in[0];
  const float* opac   = (const float*)d_in[1];
  const float* scales = (const float*)d_in[2];
  const float* rots   = (const float*)d_in[3];
  const float4* feats = (const float4*)d_in[4];

  char* ws = (char*)d_ws;
  float4* pack   = (float4*)ws;                       // 512 KB
  int* tileCnt   = (int*)(ws + 512 * 1024);           // 6.4 KB
  int* tileList  = (int*)(ws + 520 * 1024);           // 1.6 MB

  hipMemsetAsync(tileCnt, 0, NTILES * sizeof(int), stream);
  gv_precompute_bin<<<128, 64, 0, stream>>>(means, opac, scales, rots,
                                            pack, tileCnt, tileList);
  dim3 grid(TTZ, TTY, TTX);
  gv_voxelize<<<grid, 256, 0, stream>>>(pack, feats, tileCnt, tileList,
                                        (float4*)d_out);
}